// Round 5
// baseline (2370.897 us; speedup 1.0000x reference)
//
#include <hip/hip_runtime.h>
#include <hip/hip_bf16.h>

// B=1024, F=1024, S=64, 64 steps.
//   base   = q @ Wq_perm^T + (b_ih+b_hh)_perm     (once, f32, permuted cols)
//   Wcomb  = [W_hh | (support@Wr^T)^T]_perm rows  (once, bf16, K=1088)
//   step:  attn cols of X  = softmax(h_bf @ support^T)    (attn_kernel)
//          gates = X @ Wcomb^T + base  -> fused LSTM -> c, h(bf16 into Xnext)
// GEMM: BM=128 x BN=128, 256 blocks, **8 waves (512 thr) = 2 waves/SIMD** for
// intra-block SIMD overlap; wave tile 32x64 (2x4 frags); 3-buf LDS, depth-2
// prefetch, counted vmcnt(2); setprio(1) around MFMA cluster (T5).

typedef __attribute__((ext_vector_type(8))) __bf16 bf16x8;
typedef __attribute__((ext_vector_type(4))) float f32x4;
typedef __attribute__((ext_vector_type(8))) unsigned short ushort8;

__device__ __forceinline__ ushort f2bf(float f) {
  union { float f; unsigned int u; } v; v.f = f;
  unsigned int u = v.u;
  u += 0x7FFFu + ((u >> 16) & 1u);   // RNE
  return (ushort)(u >> 16);
}
__device__ __forceinline__ float bf2f(ushort u) {
  union { float f; unsigned int u; } v; v.u = ((unsigned int)u) << 16; return v.f;
}
__device__ __forceinline__ float sigm_(float x) { return 1.f / (1.f + __expf(-x)); }
__device__ __forceinline__ float tanh_(float x) {
  x = fminf(15.f, fmaxf(-15.f, x));
  float e = __expf(2.f * x);
  return (e - 1.f) / (e + 1.f);
}
__device__ __forceinline__ void async16(ushort* lds, const ushort* g) {
  __builtin_amdgcn_global_load_lds(
      (const __attribute__((address_space(1))) void*)g,
      (__attribute__((address_space(3))) void*)lds, 16, 0, 0);
}
__device__ __forceinline__ int permrow(int n) {   // n = gate*1024 + j
  int g = n >> 10, j = n & 1023;
  return ((j >> 4) << 6) | (g << 4) | (j & 15);
}

// ---------------- precompute ------------------------------------------------
__global__ __launch_bounds__(256) void prep_kernel(
    const float* __restrict__ query, const float* __restrict__ support,
    const float* __restrict__ W_ih, const float* __restrict__ W_hh,
    const float* __restrict__ b_ih, const float* __restrict__ b_hh,
    ushort* __restrict__ Wq_bf, ushort* __restrict__ Wcomb,
    float* __restrict__ bias_p, ushort* __restrict__ X0,
    float* __restrict__ c, float* __restrict__ sT,
    ushort* __restrict__ Wr_bf, ushort* __restrict__ Sb)
{
  int g = blockIdx.x * 256 + threadIdx.x;        // 0 .. 4M-1
  int n = g >> 10, k = g & 1023;
  int np = permrow(n);
  Wq_bf[(size_t)np * 1024 + k] = f2bf(W_ih[(size_t)n * 2048 + k]);
  Wr_bf[(size_t)n * 1024 + k]  = f2bf(W_ih[(size_t)n * 2048 + 1024 + k]);
  Wcomb[(size_t)np * 1088 + k] = f2bf(W_hh[(size_t)n * 1024 + k]);
  if (g < 1024 * 1024) {
    X0[(size_t)(g >> 10) * 1088 + (g & 1023)] = f2bf(query[g]);
    c[g] = 0.f;
  }
  if (g < 4096) bias_p[permrow(g)] = b_ih[g] + b_hh[g];
  if (g < 65536) {
    int kk = g >> 6, s = g & 63;
    float v = support[(size_t)s * 1024 + kk];
    sT[g] = v;                             // sT[k][s]
    Sb[(size_t)s * 1024 + kk] = f2bf(v);   // bf16 row-major support
  }
}

// ---- SW^T via MFMA: C[n][s] = sum_k Wr_bf[n][k]*Sb[s][k] -> Wcomb perm cols
__global__ __launch_bounds__(256) void sw_mfma(
    const ushort* __restrict__ Wr, const ushort* __restrict__ Sb,
    ushort* __restrict__ Wcomb)
{
  __shared__ ushort As[3][128 * 32];   // 24 KB
  __shared__ ushort Bs[3][64 * 32];    // 12 KB
  const int t = threadIdx.x;
  const int bm0 = blockIdx.x * 128;
  const int w = t >> 6, l = t & 63;
  const int wm = w * 32;
  const int srow = t >> 2, scol = (t & 3) * 8;
  const ushort* ga0 = Wr + (size_t)(bm0 + srow) * 1024 + scol;
  const ushort* ga1 = Wr + (size_t)(bm0 + 64 + srow) * 1024 + scol;
  const ushort* gb0 = Sb + (size_t)srow * 1024 + scol;   // srow<64 rows, ldb=1024
  const int fr = l & 15, fk = (l >> 4) * 8, fq = l >> 4;
  f32x4 acc[2][4] = {};
  const int nt = 32;   // K=1024
  async16(&As[0][t * 8], ga0); async16(&As[0][2048 + t * 8], ga1);
  async16(&Bs[0][t * 8], gb0);
  async16(&As[1][t * 8], ga0 + 32); async16(&As[1][2048 + t * 8], ga1 + 32);
  async16(&Bs[1][t * 8], gb0 + 32);
  for (int it = 0; it < nt; it++) {
    if (it + 1 < nt) { asm volatile("s_waitcnt vmcnt(3)" ::: "memory"); }
    else             { asm volatile("s_waitcnt vmcnt(0)" ::: "memory"); }
    __builtin_amdgcn_s_barrier();
    __builtin_amdgcn_sched_barrier(0);
    const int b = it % 3;
    const ushort* pa = &As[b][(wm + fr) * 32 + fk];
    const ushort* pb = &Bs[b][fr * 32 + fk];
    bf16x8 af[2], bfv[4];
#pragma unroll
    for (int mi = 0; mi < 2; mi++) af[mi] = *(const bf16x8*)(pa + mi * 512);
#pragma unroll
    for (int ni = 0; ni < 4; ni++) bfv[ni] = *(const bf16x8*)(pb + ni * 512);
    if (it + 2 < nt) {
      const int pbuf = (it + 2) % 3;
      const int k0 = (it + 2) << 5;
      async16(&As[pbuf][t * 8], ga0 + k0); async16(&As[pbuf][2048 + t * 8], ga1 + k0);
      async16(&Bs[pbuf][t * 8], gb0 + k0);
    }
#pragma unroll
    for (int mi = 0; mi < 2; mi++)
#pragma unroll
      for (int ni = 0; ni < 4; ni++)
        acc[mi][ni] = __builtin_amdgcn_mfma_f32_16x16x32_bf16(af[mi], bfv[ni], acc[mi][ni], 0, 0, 0);
  }
#pragma unroll
  for (int mi = 0; mi < 2; mi++)
#pragma unroll
    for (int ni = 0; ni < 4; ni++) {
      int s = ni * 16 + fr;
      int row0 = bm0 + wm + mi * 16 + fq * 4;
#pragma unroll
      for (int jj = 0; jj < 4; jj++)
        Wcomb[(size_t)permrow(row0 + jj) * 1088 + 1024 + s] = f2bf(acc[mi][ni][jj]);
    }
}

// ---------------- per-step attention (4 rows/block, 256 blocks) -------------
__global__ __launch_bounds__(256) void attn_kernel(
    const ushort* __restrict__ Xh, const float* __restrict__ sT,
    ushort* __restrict__ Xa)
{
  __shared__ float hs[4][1024];       // 16 KB
  __shared__ float part[4][4][64];    // 4 KB
  int t = threadIdx.x;
  int b0 = blockIdx.x * 4;
#pragma unroll
  for (int i = 0; i < 2; i++) {
    int r = i * 2 + (t >> 7), c8 = (t & 127) << 3;
    ushort8 v = *(const ushort8*)&Xh[(size_t)(b0 + r) * 1088 + c8];
#pragma unroll
    for (int jj = 0; jj < 8; jj++) hs[r][c8 + jj] = bf2f(v[jj]);
  }
  __syncthreads();
  int s = t & 63, q = t >> 6;
  const float* st = sT + (size_t)q * 256 * 64 + s;
  const float* hp0 = &hs[0][q * 256];
  const float* hp1 = &hs[1][q * 256];
  const float* hp2 = &hs[2][q * 256];
  const float* hp3 = &hs[3][q * 256];
  float a0 = 0.f, a1 = 0.f, a2 = 0.f, a3 = 0.f;
#pragma unroll 4
  for (int kk = 0; kk < 256; kk += 4) {
    float s0 = st[(size_t)kk * 64], s1 = st[(size_t)(kk + 1) * 64];
    float s2 = st[(size_t)(kk + 2) * 64], s3 = st[(size_t)(kk + 3) * 64];
    float4 h0 = *(const float4*)&hp0[kk];
    float4 h1 = *(const float4*)&hp1[kk];
    float4 h2 = *(const float4*)&hp2[kk];
    float4 h3 = *(const float4*)&hp3[kk];
    a0 += h0.x * s0 + h0.y * s1 + h0.z * s2 + h0.w * s3;
    a1 += h1.x * s0 + h1.y * s1 + h1.z * s2 + h1.w * s3;
    a2 += h2.x * s0 + h2.y * s1 + h2.z * s2 + h2.w * s3;
    a3 += h3.x * s0 + h3.y * s1 + h3.z * s2 + h3.w * s3;
  }
  part[q][0][s] = a0; part[q][1][s] = a1; part[q][2][s] = a2; part[q][3][s] = a3;
  __syncthreads();
  {
    int r = t >> 6, s2 = t & 63;     // one row per wave
    float v = part[0][r][s2] + part[1][r][s2] + part[2][r][s2] + part[3][r][s2];
    float m = v;
    for (int off = 32; off; off >>= 1) m = fmaxf(m, __shfl_xor(m, off));
    float e = __expf(v - m);
    float sm = e;
    for (int off = 32; off; off >>= 1) sm += __shfl_xor(sm, off);
    Xa[(size_t)(b0 + r) * 1088 + 1024 + s2] = f2bf(e / sm);
  }
}

// ---------------- GEMM 128x128, 8 waves, 3-buf depth-2, vmcnt(2) ------------
// wave tile 32x64 (2x4 frags). setprio around MFMA cluster.
// mode0 (base==null): Cout[row][col] = acc + bias[col]
// mode1: fused LSTM; writes c, Xout h-part (bf16), optional f32 out
__global__ __launch_bounds__(512) void gemm_step(
    const ushort* __restrict__ A, const ushort* __restrict__ Bw,
    int lda, int ldb, int K,
    const float* __restrict__ base, const float* __restrict__ bias,
    float* __restrict__ Cout,
    float* __restrict__ cbuf, const float* __restrict__ query,
    ushort* __restrict__ Xout, float* __restrict__ outp)
{
  __shared__ ushort As[3][128 * 32];   // 24 KB
  __shared__ ushort Bs[3][128 * 32];   // 24 KB
  const int t = threadIdx.x;
  // 256 blocks; XCD xcd owns by in [xcd*4, xcd*4+4) x all 8 bx  (3.3 MB/L2)
  const int bid = blockIdx.x;
  const int xcd = bid & 7, i = bid >> 3;        // i 0..31
  const int by = xcd * 4 + (i >> 3), bx = i & 7;
  const int m0 = bx * 128, n0 = by * 128;
  const int w = t >> 6, l = t & 63;
  const int wm = (w >> 1) * 32, wn = (w & 1) * 64;   // 4x2 wave grid
  const int srow = t >> 2, scol = (t & 3) * 8;       // 512 thr cover 128x32
  const ushort* ga = A  + (size_t)(m0 + srow) * lda + scol;
  const ushort* gb = Bw + (size_t)(n0 + srow) * ldb + scol;
  const int fr = l & 15, fk = (l >> 4) * 8, fq = l >> 4;
  f32x4 acc[2][4] = {};
  const int nt = K >> 5;   // 2 VMEM instrs per wave per tile
  // prologue: tiles 0,1 in flight (4 VMEM instrs)
  async16(&As[0][t * 8], ga);      async16(&Bs[0][t * 8], gb);
  async16(&As[1][t * 8], ga + 32); async16(&Bs[1][t * 8], gb + 32);
  for (int it = 0; it < nt; it++) {
    if (it + 1 < nt) { asm volatile("s_waitcnt vmcnt(2)" ::: "memory"); }
    else             { asm volatile("s_waitcnt vmcnt(0)" ::: "memory"); }
    __builtin_amdgcn_s_barrier();
    __builtin_amdgcn_sched_barrier(0);
    if (it + 2 < nt) {   // issue next-next tile first (stage-before-read)
      const int pbuf = (it + 2) % 3;
      const int k0 = (it + 2) << 5;
      async16(&As[pbuf][t * 8], ga + k0);
      async16(&Bs[pbuf][t * 8], gb + k0);
    }
    const int b = it % 3;
    const ushort* pa = &As[b][(wm + fr) * 32 + fk];
    const ushort* pb = &Bs[b][(wn + fr) * 32 + fk];
    bf16x8 af[2], bfv[4];
#pragma unroll
    for (int mi = 0; mi < 2; mi++) af[mi] = *(const bf16x8*)(pa + mi * 512);
#pragma unroll
    for (int ni = 0; ni < 4; ni++) bfv[ni] = *(const bf16x8*)(pb + ni * 512);
    __builtin_amdgcn_s_setprio(1);
#pragma unroll
    for (int mi = 0; mi < 2; mi++)
#pragma unroll
      for (int ni = 0; ni < 4; ni++)
        acc[mi][ni] = __builtin_amdgcn_mfma_f32_16x16x32_bf16(af[mi], bfv[ni], acc[mi][ni], 0, 0, 0);
    __builtin_amdgcn_s_setprio(0);
  }
  if (!base) {            // mode0: plain C = acc + bias
#pragma unroll
    for (int mi = 0; mi < 2; mi++)
#pragma unroll
      for (int ni = 0; ni < 4; ni++) {
        int col = n0 + wn + ni * 16 + fr;
        int row0 = m0 + wm + mi * 16 + fq * 4;
        float bv = bias[col];
#pragma unroll
        for (int jj = 0; jj < 4; jj++)
          Cout[(size_t)(row0 + jj) * 4096 + col] = acc[mi][ni][jj] + bv;
      }
    return;
  }
  // mode1: lane-local LSTM. acc[mi][ni] = gate ni (i,f,g,o) for j = jbase+fr
  const int jbase = (((n0 + wn) >> 6) << 4);
  const int jcol = jbase + fr;
#pragma unroll
  for (int mi = 0; mi < 2; mi++) {
#pragma unroll
    for (int jj = 0; jj < 4; jj++) {
      int row = m0 + wm + mi * 16 + fq * 4 + jj;
      const float* bp = base + (size_t)row * 4096 + (n0 + wn);
      float gi = acc[mi][0][jj] + bp[fr];
      float gf = acc[mi][1][jj] + bp[16 + fr];
      float gg = acc[mi][2][jj] + bp[32 + fr];
      float go = acc[mi][3][jj] + bp[48 + fr];
      size_t cidx = (size_t)row * 1024 + jcol;
      float cv = cbuf[cidx];
      float cn = sigm_(gf) * cv + sigm_(gi) * tanh_(gg);
      float hn = sigm_(go) * tanh_(cn) + query[cidx];
      cbuf[cidx] = cn;
      Xout[(size_t)row * 1088 + jcol] = f2bf(hn);
      if (outp) outp[cidx] = hn;
    }
  }
}

extern "C" void kernel_launch(void* const* d_in, const int* in_sizes, int n_in,
                              void* d_out, int out_size, void* d_ws, size_t ws_size,
                              hipStream_t stream) {
  const float* query   = (const float*)d_in[0];
  const float* support = (const float*)d_in[1];
  const float* W_ih    = (const float*)d_in[2];
  const float* W_hh    = (const float*)d_in[3];
  const float* b_ih    = (const float*)d_in[4];
  const float* b_hh    = (const float*)d_in[5];
  float* out = (float*)d_out;

  char* ws = (char*)d_ws;
  size_t off = 0;
  auto alloc = [&](size_t bytes) {
    void* p = ws + off;
    off += (bytes + 255) & ~(size_t)255;
    return p;
  };
  ushort* Wq_bf  = (ushort*)alloc((size_t)4096 * 1024 * 2);
  ushort* Wcomb  = (ushort*)alloc((size_t)4096 * 1088 * 2);
  ushort* Wr_bf  = (ushort*)alloc((size_t)4096 * 1024 * 2);
  ushort* Sb     = (ushort*)alloc((size_t)64 * 1024 * 2);
  float*  bias_p = (float*) alloc((size_t)4096 * 4);
  float*  base   = (float*) alloc((size_t)1024 * 4096 * 4);
  ushort* X0     = (ushort*)alloc((size_t)1024 * 1088 * 2);
  ushort* X1     = (ushort*)alloc((size_t)1024 * 1088 * 2);
  float*  c      = (float*) alloc((size_t)1024 * 1024 * 4);
  float*  sT     = (float*) alloc((size_t)1024 * 64 * 4);

  prep_kernel<<<16384, 256, 0, stream>>>(query, support, W_ih, W_hh, b_ih, b_hh,
                                         Wq_bf, Wcomb, bias_p, X0, c, sT,
                                         Wr_bf, Sb);
  sw_mfma<<<32, 256, 0, stream>>>(Wr_bf, Sb, Wcomb);
  // base = bf16(q) @ Wq_perm^T + bias_p   (A = X0 h-part)
  gemm_step<<<256, 512, 0, stream>>>(X0, Wq_bf, 1088, 1024, 1024,
                                     nullptr, bias_p, base,
                                     nullptr, nullptr, nullptr, nullptr);
  for (int step = 0; step < 64; step++) {
    ushort* Xc = (step & 1) ? X1 : X0;
    ushort* Xn = (step & 1) ? X0 : X1;
    attn_kernel<<<256, 256, 0, stream>>>(Xc, sT, Xc);
    gemm_step<<<256, 512, 0, stream>>>(Xc, Wcomb, 1088, 1088, 1088,
                                       base, nullptr, nullptr,
                                       c, query, Xn,
                                       (step == 63) ? out : nullptr);
  }
}

// Round 6
// 2014.021 us; speedup vs baseline: 1.1772x; 1.1772x over previous
//
#include <hip/hip_runtime.h>
#include <hip/hip_bf16.h>

// B=1024, F=1024, S=64, 64 steps.
//   base   = q @ Wq_perm^T + (b_ih+b_hh)_perm     (once, f32, permuted cols)
//   Wcomb  = [W_hh | (support@Wr^T)^T]_perm rows  (once, bf16, K=1088)
//   step:  attn cols of X  = softmax(h_bf @ support^T)    (attn_kernel)
//          gates = X @ Wcomb^T + base  -> fused LSTM -> c, h(bf16 into Xnext)
// GEMM: BM=64 x BN=128, 512 blocks = 2 blocks/CU (measured best: independent
// blocks with decoupled barriers beat more waves in lockstep), 4 waves,
// wave tile 32x64. BK=64 phase = two BK=32 sub-tiles (inner stride stays 64B,
// no bank conflicts): halves barrier count, 16 MFMA/wave/phase.
// 3-buf LDS (72 KB), depth-2 prefetch, counted vmcnt(6).

typedef __attribute__((ext_vector_type(8))) __bf16 bf16x8;
typedef __attribute__((ext_vector_type(4))) float f32x4;
typedef __attribute__((ext_vector_type(8))) unsigned short ushort8;

__device__ __forceinline__ ushort f2bf(float f) {
  union { float f; unsigned int u; } v; v.f = f;
  unsigned int u = v.u;
  u += 0x7FFFu + ((u >> 16) & 1u);   // RNE
  return (ushort)(u >> 16);
}
__device__ __forceinline__ float bf2f(ushort u) {
  union { float f; unsigned int u; } v; v.u = ((unsigned int)u) << 16; return v.f;
}
__device__ __forceinline__ float sigm_(float x) { return 1.f / (1.f + __expf(-x)); }
__device__ __forceinline__ float tanh_(float x) {
  x = fminf(15.f, fmaxf(-15.f, x));
  float e = __expf(2.f * x);
  return (e - 1.f) / (e + 1.f);
}
__device__ __forceinline__ void async16(ushort* lds, const ushort* g) {
  __builtin_amdgcn_global_load_lds(
      (const __attribute__((address_space(1))) void*)g,
      (__attribute__((address_space(3))) void*)lds, 16, 0, 0);
}
__device__ __forceinline__ int permrow(int n) {   // n = gate*1024 + j
  int g = n >> 10, j = n & 1023;
  return ((j >> 4) << 6) | (g << 4) | (j & 15);
}

// ---------------- precompute ------------------------------------------------
__global__ __launch_bounds__(256) void prep_kernel(
    const float* __restrict__ query, const float* __restrict__ support,
    const float* __restrict__ W_ih, const float* __restrict__ W_hh,
    const float* __restrict__ b_ih, const float* __restrict__ b_hh,
    ushort* __restrict__ Wq_bf, ushort* __restrict__ Wcomb,
    float* __restrict__ bias_p, ushort* __restrict__ X0,
    float* __restrict__ c, float* __restrict__ sT,
    ushort* __restrict__ Wr_bf, ushort* __restrict__ Sb)
{
  int g = blockIdx.x * 256 + threadIdx.x;        // 0 .. 4M-1
  int n = g >> 10, k = g & 1023;
  int np = permrow(n);
  Wq_bf[(size_t)np * 1024 + k] = f2bf(W_ih[(size_t)n * 2048 + k]);
  Wr_bf[(size_t)n * 1024 + k]  = f2bf(W_ih[(size_t)n * 2048 + 1024 + k]);
  Wcomb[(size_t)np * 1088 + k] = f2bf(W_hh[(size_t)n * 1024 + k]);
  if (g < 1024 * 1024) {
    X0[(size_t)(g >> 10) * 1088 + (g & 1023)] = f2bf(query[g]);
    c[g] = 0.f;
  }
  if (g < 4096) bias_p[permrow(g)] = b_ih[g] + b_hh[g];
  if (g < 65536) {
    int kk = g >> 6, s = g & 63;
    float v = support[(size_t)s * 1024 + kk];
    sT[g] = v;                             // sT[k][s]
    Sb[(size_t)s * 1024 + kk] = f2bf(v);   // bf16 row-major support
  }
}

// ---- SW^T via MFMA: C[n][s] = sum_k Wr_bf[n][k]*Sb[s][k] -> Wcomb perm cols
__global__ __launch_bounds__(256) void sw_mfma(
    const ushort* __restrict__ Wr, const ushort* __restrict__ Sb,
    ushort* __restrict__ Wcomb)
{
  __shared__ ushort As[3][128 * 32];   // 24 KB
  __shared__ ushort Bs[3][64 * 32];    // 12 KB
  const int t = threadIdx.x;
  const int bm0 = blockIdx.x * 128;
  const int w = t >> 6, l = t & 63;
  const int wm = w * 32;
  const int srow = t >> 2, scol = (t & 3) * 8;
  const ushort* ga0 = Wr + (size_t)(bm0 + srow) * 1024 + scol;
  const ushort* ga1 = Wr + (size_t)(bm0 + 64 + srow) * 1024 + scol;
  const ushort* gb0 = Sb + (size_t)srow * 1024 + scol;   // srow<64 rows, ldb=1024
  const int fr = l & 15, fk = (l >> 4) * 8, fq = l >> 4;
  f32x4 acc[2][4] = {};
  const int nt = 32;   // K=1024
  async16(&As[0][t * 8], ga0); async16(&As[0][2048 + t * 8], ga1);
  async16(&Bs[0][t * 8], gb0);
  async16(&As[1][t * 8], ga0 + 32); async16(&As[1][2048 + t * 8], ga1 + 32);
  async16(&Bs[1][t * 8], gb0 + 32);
  for (int it = 0; it < nt; it++) {
    if (it + 1 < nt) { asm volatile("s_waitcnt vmcnt(3)" ::: "memory"); }
    else             { asm volatile("s_waitcnt vmcnt(0)" ::: "memory"); }
    __builtin_amdgcn_s_barrier();
    __builtin_amdgcn_sched_barrier(0);
    const int b = it % 3;
    const ushort* pa = &As[b][(wm + fr) * 32 + fk];
    const ushort* pb = &Bs[b][fr * 32 + fk];
    bf16x8 af[2], bfv[4];
#pragma unroll
    for (int mi = 0; mi < 2; mi++) af[mi] = *(const bf16x8*)(pa + mi * 512);
#pragma unroll
    for (int ni = 0; ni < 4; ni++) bfv[ni] = *(const bf16x8*)(pb + ni * 512);
    if (it + 2 < nt) {
      const int pbuf = (it + 2) % 3;
      const int k0 = (it + 2) << 5;
      async16(&As[pbuf][t * 8], ga0 + k0); async16(&As[pbuf][2048 + t * 8], ga1 + k0);
      async16(&Bs[pbuf][t * 8], gb0 + k0);
    }
#pragma unroll
    for (int mi = 0; mi < 2; mi++)
#pragma unroll
      for (int ni = 0; ni < 4; ni++)
        acc[mi][ni] = __builtin_amdgcn_mfma_f32_16x16x32_bf16(af[mi], bfv[ni], acc[mi][ni], 0, 0, 0);
  }
#pragma unroll
  for (int mi = 0; mi < 2; mi++)
#pragma unroll
    for (int ni = 0; ni < 4; ni++) {
      int s = ni * 16 + fr;
      int row0 = bm0 + wm + mi * 16 + fq * 4;
#pragma unroll
      for (int jj = 0; jj < 4; jj++)
        Wcomb[(size_t)permrow(row0 + jj) * 1088 + 1024 + s] = f2bf(acc[mi][ni][jj]);
    }
}

// ---------------- per-step attention (4 rows/block, 256 blocks) -------------
__global__ __launch_bounds__(256) void attn_kernel(
    const ushort* __restrict__ Xh, const float* __restrict__ sT,
    ushort* __restrict__ Xa)
{
  __shared__ float hs[4][1024];       // 16 KB
  __shared__ float part[4][4][64];    // 4 KB
  int t = threadIdx.x;
  int b0 = blockIdx.x * 4;
#pragma unroll
  for (int i = 0; i < 2; i++) {
    int r = i * 2 + (t >> 7), c8 = (t & 127) << 3;
    ushort8 v = *(const ushort8*)&Xh[(size_t)(b0 + r) * 1088 + c8];
#pragma unroll
    for (int jj = 0; jj < 8; jj++) hs[r][c8 + jj] = bf2f(v[jj]);
  }
  __syncthreads();
  int s = t & 63, q = t >> 6;
  const float* st = sT + (size_t)q * 256 * 64 + s;
  const float* hp0 = &hs[0][q * 256];
  const float* hp1 = &hs[1][q * 256];
  const float* hp2 = &hs[2][q * 256];
  const float* hp3 = &hs[3][q * 256];
  float a0 = 0.f, a1 = 0.f, a2 = 0.f, a3 = 0.f;
#pragma unroll 4
  for (int kk = 0; kk < 256; kk += 4) {
    float s0 = st[(size_t)kk * 64], s1 = st[(size_t)(kk + 1) * 64];
    float s2 = st[(size_t)(kk + 2) * 64], s3 = st[(size_t)(kk + 3) * 64];
    float4 h0 = *(const float4*)&hp0[kk];
    float4 h1 = *(const float4*)&hp1[kk];
    float4 h2 = *(const float4*)&hp2[kk];
    float4 h3 = *(const float4*)&hp3[kk];
    a0 += h0.x * s0 + h0.y * s1 + h0.z * s2 + h0.w * s3;
    a1 += h1.x * s0 + h1.y * s1 + h1.z * s2 + h1.w * s3;
    a2 += h2.x * s0 + h2.y * s1 + h2.z * s2 + h2.w * s3;
    a3 += h3.x * s0 + h3.y * s1 + h3.z * s2 + h3.w * s3;
  }
  part[q][0][s] = a0; part[q][1][s] = a1; part[q][2][s] = a2; part[q][3][s] = a3;
  __syncthreads();
  {
    int r = t >> 6, s2 = t & 63;     // one row per wave
    float v = part[0][r][s2] + part[1][r][s2] + part[2][r][s2] + part[3][r][s2];
    float m = v;
    for (int off = 32; off; off >>= 1) m = fmaxf(m, __shfl_xor(m, off));
    float e = __expf(v - m);
    float sm = e;
    for (int off = 32; off; off >>= 1) sm += __shfl_xor(sm, off);
    Xa[(size_t)(b0 + r) * 1088 + 1024 + s2] = f2bf(e / sm);
  }
}

// ---------------- GEMM 64x128, BK=64 (2 sub-tiles/phase), fused LSTM --------
// 4 waves, wave tile 32x64 (2x4 frags). 3-buf, depth-2, vmcnt(6).
// mode0 (base==null): Cout[row][col] = acc + bias[col]
// mode1: fused LSTM; writes c, Xout h-part (bf16), optional f32 out
__global__ __launch_bounds__(256) void gemm_step(
    const ushort* __restrict__ A, const ushort* __restrict__ Bw,
    int lda, int ldb, int K,
    const float* __restrict__ base, const float* __restrict__ bias,
    float* __restrict__ Cout,
    float* __restrict__ cbuf, const float* __restrict__ query,
    ushort* __restrict__ Xout, float* __restrict__ outp)
{
  __shared__ ushort As[3][2][64 * 32];    // 24 KB
  __shared__ ushort Bs[3][2][128 * 32];   // 48 KB
  const int t = threadIdx.x;
  // 512 blocks; XCD xcd owns by in [xcd*4, xcd*4+4) x all 16 bx (3.3 MB/L2)
  const int bid = blockIdx.x;
  const int xcd = bid & 7, idx = bid >> 3;
  const int bx = idx & 15, byy = idx >> 4;
  const int by = xcd * 4 + byy;
  const int m0 = bx * 64, n0 = by * 128;
  const int w = t >> 6, l = t & 63;
  const int wm = (w >> 1) * 32, wn = (w & 1) * 64;
  const int srow = t >> 2, scol = (t & 3) * 8;
  const ushort* ga  = A  + (size_t)(m0 + srow) * lda + scol;
  const ushort* gb0 = Bw + (size_t)(n0 + srow) * ldb + scol;
  const ushort* gb1 = Bw + (size_t)(n0 + 64 + srow) * ldb + scol;
  const int fr = l & 15, fk = (l >> 4) * 8, fq = l >> 4;
  f32x4 acc[2][4] = {};
  const int nt = K >> 6;   // BK=64 phases; 6 VMEM instrs per thread per phase
#define STAGE(buf, k0)                                        \
  async16(&As[buf][0][t * 8], ga + (k0));                     \
  async16(&As[buf][1][t * 8], ga + (k0) + 32);                \
  async16(&Bs[buf][0][t * 8], gb0 + (k0));                    \
  async16(&Bs[buf][0][2048 + t * 8], gb1 + (k0));             \
  async16(&Bs[buf][1][t * 8], gb0 + (k0) + 32);               \
  async16(&Bs[buf][1][2048 + t * 8], gb1 + (k0) + 32);
  // prologue: tiles 0,1 in flight (12 VMEM instrs)
  STAGE(0, 0)
  STAGE(1, 64)
  for (int it = 0; it < nt; it++) {
    if (it + 1 < nt) { asm volatile("s_waitcnt vmcnt(6)" ::: "memory"); }
    else             { asm volatile("s_waitcnt vmcnt(0)" ::: "memory"); }
    __builtin_amdgcn_s_barrier();
    __builtin_amdgcn_sched_barrier(0);
    if (it + 2 < nt) {   // depth-2 prefetch first (stage-before-read)
      const int pbuf = (it + 2) % 3;
      const int k0 = (it + 2) << 6;
      STAGE(pbuf, k0)
    }
    const int b = it % 3;
#pragma unroll
    for (int kk = 0; kk < 2; kk++) {
      const ushort* pa = &As[b][kk][(wm + fr) * 32 + fk];
      const ushort* pb = &Bs[b][kk][(wn + fr) * 32 + fk];
      bf16x8 af[2], bfv[4];
#pragma unroll
      for (int mi = 0; mi < 2; mi++) af[mi] = *(const bf16x8*)(pa + mi * 512);
#pragma unroll
      for (int ni = 0; ni < 4; ni++) bfv[ni] = *(const bf16x8*)(pb + ni * 512);
      __builtin_amdgcn_s_setprio(1);
#pragma unroll
      for (int mi = 0; mi < 2; mi++)
#pragma unroll
        for (int ni = 0; ni < 4; ni++)
          acc[mi][ni] = __builtin_amdgcn_mfma_f32_16x16x32_bf16(af[mi], bfv[ni], acc[mi][ni], 0, 0, 0);
      __builtin_amdgcn_s_setprio(0);
    }
  }
#undef STAGE
  if (!base) {            // mode0: plain C = acc + bias
#pragma unroll
    for (int mi = 0; mi < 2; mi++)
#pragma unroll
      for (int ni = 0; ni < 4; ni++) {
        int col = n0 + wn + ni * 16 + fr;
        int row0 = m0 + wm + mi * 16 + fq * 4;
        float bv = bias[col];
#pragma unroll
        for (int jj = 0; jj < 4; jj++)
          Cout[(size_t)(row0 + jj) * 4096 + col] = acc[mi][ni][jj] + bv;
      }
    return;
  }
  // mode1: lane-local LSTM. acc[mi][ni] = gate ni (i,f,g,o) for j = jbase+fr
  const int jbase = (((n0 + wn) >> 6) << 4);
  const int jcol = jbase + fr;
#pragma unroll
  for (int mi = 0; mi < 2; mi++) {
#pragma unroll
    for (int jj = 0; jj < 4; jj++) {
      int row = m0 + wm + mi * 16 + fq * 4 + jj;
      const float* bp = base + (size_t)row * 4096 + (n0 + wn);
      float gi = acc[mi][0][jj] + bp[fr];
      float gf = acc[mi][1][jj] + bp[16 + fr];
      float gg = acc[mi][2][jj] + bp[32 + fr];
      float go = acc[mi][3][jj] + bp[48 + fr];
      size_t cidx = (size_t)row * 1024 + jcol;
      float cv = cbuf[cidx];
      float cn = sigm_(gf) * cv + sigm_(gi) * tanh_(gg);
      float hn = sigm_(go) * tanh_(cn) + query[cidx];
      cbuf[cidx] = cn;
      Xout[(size_t)row * 1088 + jcol] = f2bf(hn);
      if (outp) outp[cidx] = hn;
    }
  }
}

extern "C" void kernel_launch(void* const* d_in, const int* in_sizes, int n_in,
                              void* d_out, int out_size, void* d_ws, size_t ws_size,
                              hipStream_t stream) {
  const float* query   = (const float*)d_in[0];
  const float* support = (const float*)d_in[1];
  const float* W_ih    = (const float*)d_in[2];
  const float* W_hh    = (const float*)d_in[3];
  const float* b_ih    = (const float*)d_in[4];
  const float* b_hh    = (const float*)d_in[5];
  float* out = (float*)d_out;

  char* ws = (char*)d_ws;
  size_t off = 0;
  auto alloc = [&](size_t bytes) {
    void* p = ws + off;
    off += (bytes + 255) & ~(size_t)255;
    return p;
  };
  ushort* Wq_bf  = (ushort*)alloc((size_t)4096 * 1024 * 2);
  ushort* Wcomb  = (ushort*)alloc((size_t)4096 * 1088 * 2);
  ushort* Wr_bf  = (ushort*)alloc((size_t)4096 * 1024 * 2);
  ushort* Sb     = (ushort*)alloc((size_t)64 * 1024 * 2);
  float*  bias_p = (float*) alloc((size_t)4096 * 4);
  float*  base   = (float*) alloc((size_t)1024 * 4096 * 4);
  ushort* X0     = (ushort*)alloc((size_t)1024 * 1088 * 2);
  ushort* X1     = (ushort*)alloc((size_t)1024 * 1088 * 2);
  float*  c      = (float*) alloc((size_t)1024 * 1024 * 4);
  float*  sT     = (float*) alloc((size_t)1024 * 64 * 4);

  prep_kernel<<<16384, 256, 0, stream>>>(query, support, W_ih, W_hh, b_ih, b_hh,
                                         Wq_bf, Wcomb, bias_p, X0, c, sT,
                                         Wr_bf, Sb);
  sw_mfma<<<32, 256, 0, stream>>>(Wr_bf, Sb, Wcomb);
  // base = bf16(q) @ Wq_perm^T + bias_p   (A = X0 h-part, K=1024)
  gemm_step<<<512, 256, 0, stream>>>(X0, Wq_bf, 1088, 1024, 1024,
                                     nullptr, bias_p, base,
                                     nullptr, nullptr, nullptr, nullptr);
  for (int step = 0; step < 64; step++) {
    ushort* Xc = (step & 1) ? X1 : X0;
    ushort* Xn = (step & 1) ? X0 : X1;
    attn_kernel<<<256, 256, 0, stream>>>(Xc, sT, Xc);
    gemm_step<<<512, 256, 0, stream>>>(Xc, Wcomb, 1088, 1088, 1088,
                                       base, nullptr, nullptr,
                                       c, query, Xn,
                                       (step == 63) ? out : nullptr);
  }
}

// Round 7
// 1944.951 us; speedup vs baseline: 1.2190x; 1.0355x over previous
//
#include <hip/hip_runtime.h>
#include <hip/hip_bf16.h>

// B=1024, F=1024, S=64, 64 steps.
//   base   = q @ Wq_perm^T + (b_ih+b_hh)_perm     (once, f32, permuted cols)
//   Wcomb  = [W_hh | (support@Wr^T)^T]_perm rows  (once, bf16, K=1088)
//   step (ONE kernel): 17-phase gemm gates = [h|attn] @ Wcomb^T + base.
//     Phases 0..15 (k=h): main MFMA (16/wave) + fused logits MFMA (8/wave,
//     B-frags = Sb from L2->regs). After phase 15: in-LDS softmax of the
//     block's own 64 rows -> attn bf16 written into the phase-16 A-slot.
//     Phase 16 (k=attn x SW^T). Epilogue: lane-local LSTM -> c, h.
//   No separate attention kernel; X holds h only (1024 cols).
// GEMM: BM=64 x BN=128, 512 blocks = 2/CU, 4 waves, wave 32x64.
// 3-buf LDS (72 KB), counted vmcnt (6/4/0 by phase), setprio on MFMA.

typedef __attribute__((ext_vector_type(8))) __bf16 bf16x8;
typedef __attribute__((ext_vector_type(4))) float f32x4;
typedef __attribute__((ext_vector_type(8))) unsigned short ushort8;

__device__ __forceinline__ ushort f2bf(float f) {
  union { float f; unsigned int u; } v; v.f = f;
  unsigned int u = v.u;
  u += 0x7FFFu + ((u >> 16) & 1u);   // RNE
  return (ushort)(u >> 16);
}
__device__ __forceinline__ float bf2f(ushort u) {
  union { float f; unsigned int u; } v; v.u = ((unsigned int)u) << 16; return v.f;
}
__device__ __forceinline__ float sigm_(float x) { return 1.f / (1.f + __expf(-x)); }
__device__ __forceinline__ float tanh_(float x) {
  x = fminf(15.f, fmaxf(-15.f, x));
  float e = __expf(2.f * x);
  return (e - 1.f) / (e + 1.f);
}
__device__ __forceinline__ void async16(ushort* lds, const ushort* g) {
  __builtin_amdgcn_global_load_lds(
      (const __attribute__((address_space(1))) void*)g,
      (__attribute__((address_space(3))) void*)lds, 16, 0, 0);
}
__device__ __forceinline__ int permrow(int n) {   // n = gate*1024 + j
  int g = n >> 10, j = n & 1023;
  return ((j >> 4) << 6) | (g << 4) | (j & 15);
}

// ---------------- precompute ------------------------------------------------
__global__ __launch_bounds__(256) void prep_kernel(
    const float* __restrict__ query, const float* __restrict__ support,
    const float* __restrict__ W_ih, const float* __restrict__ W_hh,
    const float* __restrict__ b_ih, const float* __restrict__ b_hh,
    ushort* __restrict__ Wq_bf, ushort* __restrict__ Wcomb,
    float* __restrict__ bias_p, ushort* __restrict__ X0,
    float* __restrict__ c, ushort* __restrict__ Wr_bf,
    ushort* __restrict__ Sb)
{
  int g = blockIdx.x * 256 + threadIdx.x;        // 0 .. 4M-1
  int n = g >> 10, k = g & 1023;
  int np = permrow(n);
  Wq_bf[(size_t)np * 1024 + k] = f2bf(W_ih[(size_t)n * 2048 + k]);
  Wr_bf[(size_t)n * 1024 + k]  = f2bf(W_ih[(size_t)n * 2048 + 1024 + k]);
  Wcomb[(size_t)np * 1088 + k] = f2bf(W_hh[(size_t)n * 1024 + k]);
  if (g < 1024 * 1024) {
    X0[g] = f2bf(query[g]);
    c[g] = 0.f;
  }
  if (g < 4096) bias_p[permrow(g)] = b_ih[g] + b_hh[g];
  if (g < 65536) Sb[g] = f2bf(support[g]);     // bf16 row-major support [64][1024]
}

// ---- SW^T via MFMA: C[n][s] = sum_k Wr_bf[n][k]*Sb[s][k] -> Wcomb perm cols
__global__ __launch_bounds__(256) void sw_mfma(
    const ushort* __restrict__ Wr, const ushort* __restrict__ Sb,
    ushort* __restrict__ Wcomb)
{
  __shared__ ushort As[3][128 * 32];   // 24 KB
  __shared__ ushort Bs[3][64 * 32];    // 12 KB
  const int t = threadIdx.x;
  const int bm0 = blockIdx.x * 128;
  const int w = t >> 6, l = t & 63;
  const int wm = w * 32;
  const int srow = t >> 2, scol = (t & 3) * 8;
  const ushort* ga0 = Wr + (size_t)(bm0 + srow) * 1024 + scol;
  const ushort* ga1 = Wr + (size_t)(bm0 + 64 + srow) * 1024 + scol;
  const ushort* gb0 = Sb + (size_t)srow * 1024 + scol;
  const int fr = l & 15, fk = (l >> 4) * 8, fq = l >> 4;
  f32x4 acc[2][4] = {};
  const int nt = 32;   // K=1024
  async16(&As[0][t * 8], ga0); async16(&As[0][2048 + t * 8], ga1);
  async16(&Bs[0][t * 8], gb0);
  async16(&As[1][t * 8], ga0 + 32); async16(&As[1][2048 + t * 8], ga1 + 32);
  async16(&Bs[1][t * 8], gb0 + 32);
  for (int it = 0; it < nt; it++) {
    if (it + 1 < nt) { asm volatile("s_waitcnt vmcnt(3)" ::: "memory"); }
    else             { asm volatile("s_waitcnt vmcnt(0)" ::: "memory"); }
    __builtin_amdgcn_s_barrier();
    __builtin_amdgcn_sched_barrier(0);
    const int b = it % 3;
    const ushort* pa = &As[b][(wm + fr) * 32 + fk];
    const ushort* pb = &Bs[b][fr * 32 + fk];
    bf16x8 af[2], bfv[4];
#pragma unroll
    for (int mi = 0; mi < 2; mi++) af[mi] = *(const bf16x8*)(pa + mi * 512);
#pragma unroll
    for (int ni = 0; ni < 4; ni++) bfv[ni] = *(const bf16x8*)(pb + ni * 512);
    if (it + 2 < nt) {
      const int pbuf = (it + 2) % 3;
      const int k0 = (it + 2) << 5;
      async16(&As[pbuf][t * 8], ga0 + k0); async16(&As[pbuf][2048 + t * 8], ga1 + k0);
      async16(&Bs[pbuf][t * 8], gb0 + k0);
    }
#pragma unroll
    for (int mi = 0; mi < 2; mi++)
#pragma unroll
      for (int ni = 0; ni < 4; ni++)
        acc[mi][ni] = __builtin_amdgcn_mfma_f32_16x16x32_bf16(af[mi], bfv[ni], acc[mi][ni], 0, 0, 0);
  }
#pragma unroll
  for (int mi = 0; mi < 2; mi++)
#pragma unroll
    for (int ni = 0; ni < 4; ni++) {
      int s = ni * 16 + fr;
      int row0 = bm0 + wm + mi * 16 + fq * 4;
#pragma unroll
      for (int jj = 0; jj < 4; jj++)
        Wcomb[(size_t)permrow(row0 + jj) * 1088 + 1024 + s] = f2bf(acc[mi][ni][jj]);
    }
}

// ---------------- base GEMM (once): base = X0 @ Wq^T + bias  ---------------
__global__ __launch_bounds__(256) void gemm_base(
    const ushort* __restrict__ A, const ushort* __restrict__ Bw,
    const float* __restrict__ bias, float* __restrict__ Cout)
{
  __shared__ ushort As[3][2][64 * 32];
  __shared__ ushort Bs[3][2][128 * 32];
  const int t = threadIdx.x;
  const int bid = blockIdx.x;
  const int xcd = bid & 7, idx = bid >> 3;
  const int bx = idx & 15, byy = idx >> 4;
  const int by = xcd * 4 + byy;
  const int m0 = bx * 64, n0 = by * 128;
  const int w = t >> 6, l = t & 63;
  const int wm = (w >> 1) * 32, wn = (w & 1) * 64;
  const int srow = t >> 2, scol = (t & 3) * 8;
  const ushort* ga  = A  + (size_t)(m0 + srow) * 1024 + scol;
  const ushort* gb0 = Bw + (size_t)(n0 + srow) * 1024 + scol;
  const ushort* gb1 = Bw + (size_t)(n0 + 64 + srow) * 1024 + scol;
  const int fr = l & 15, fk = (l >> 4) * 8, fq = l >> 4;
  f32x4 acc[2][4] = {};
  const int nt = 16;
#define BSTAGE(buf, k0)                                       \
  async16(&As[buf][0][t * 8], ga + (k0));                     \
  async16(&As[buf][1][t * 8], ga + (k0) + 32);                \
  async16(&Bs[buf][0][t * 8], gb0 + (k0));                    \
  async16(&Bs[buf][0][2048 + t * 8], gb1 + (k0));             \
  async16(&Bs[buf][1][t * 8], gb0 + (k0) + 32);               \
  async16(&Bs[buf][1][2048 + t * 8], gb1 + (k0) + 32);
  BSTAGE(0, 0)
  BSTAGE(1, 64)
  for (int it = 0; it < nt; it++) {
    if (it + 1 < nt) { asm volatile("s_waitcnt vmcnt(6)" ::: "memory"); }
    else             { asm volatile("s_waitcnt vmcnt(0)" ::: "memory"); }
    __builtin_amdgcn_s_barrier();
    __builtin_amdgcn_sched_barrier(0);
    if (it + 2 < nt) { const int pb = (it + 2) % 3; const int k0 = (it + 2) << 6; BSTAGE(pb, k0) }
    const int b = it % 3;
#pragma unroll
    for (int kk = 0; kk < 2; kk++) {
      const ushort* pa = &As[b][kk][(wm + fr) * 32 + fk];
      const ushort* pb2 = &Bs[b][kk][(wn + fr) * 32 + fk];
      bf16x8 af[2], bfv[4];
#pragma unroll
      for (int mi = 0; mi < 2; mi++) af[mi] = *(const bf16x8*)(pa + mi * 512);
#pragma unroll
      for (int ni = 0; ni < 4; ni++) bfv[ni] = *(const bf16x8*)(pb2 + ni * 512);
      __builtin_amdgcn_s_setprio(1);
#pragma unroll
      for (int mi = 0; mi < 2; mi++)
#pragma unroll
        for (int ni = 0; ni < 4; ni++)
          acc[mi][ni] = __builtin_amdgcn_mfma_f32_16x16x32_bf16(af[mi], bfv[ni], acc[mi][ni], 0, 0, 0);
      __builtin_amdgcn_s_setprio(0);
    }
  }
#undef BSTAGE
#pragma unroll
  for (int mi = 0; mi < 2; mi++)
#pragma unroll
    for (int ni = 0; ni < 4; ni++) {
      int col = n0 + wn + ni * 16 + fr;
      int row0 = m0 + wm + mi * 16 + fq * 4;
      float bv = bias[col];
#pragma unroll
      for (int jj = 0; jj < 4; jj++)
        Cout[(size_t)(row0 + jj) * 4096 + col] = acc[mi][ni][jj] + bv;
    }
}

// ------------- fused per-step kernel: gemm + in-flight attention + LSTM -----
__global__ __launch_bounds__(256, 2) void gemm_fused(
    const ushort* __restrict__ A,        // Xc: h(t) [1024][1024] bf16
    const ushort* __restrict__ Wcomb,    // [4096][1088] bf16 (perm rows)
    const ushort* __restrict__ Sb,       // support [64][1024] bf16
    const float* __restrict__ base,
    float* __restrict__ cbuf, const float* __restrict__ query,
    ushort* __restrict__ Xout, float* __restrict__ outp)
{
  __shared__ ushort As[3][2][64 * 32];    // 24 KB
  __shared__ ushort Bs[3][2][128 * 32];   // 48 KB
  const int t = threadIdx.x;
  const int bid = blockIdx.x;
  const int xcd = bid & 7, idx = bid >> 3;
  const int bx = idx & 15, byy = idx >> 4;
  const int by = xcd * 4 + byy;
  const int m0 = bx * 64, n0 = by * 128;
  const int w = t >> 6, l = t & 63;
  const int wm = (w >> 1) * 32, wn = (w & 1) * 64;
  const int srow = t >> 2, scol = (t & 3) * 8;
  const ushort* ga  = A + (size_t)(m0 + srow) * 1024 + scol;
  const ushort* gb0 = Wcomb + (size_t)(n0 + srow) * 1088 + scol;
  const ushort* gb1 = Wcomb + (size_t)(n0 + 64 + srow) * 1088 + scol;
  const int fr = l & 15, fk = (l >> 4) * 8, fq = l >> 4;
  // Sb fragment base for this wave: s-rows (w&1)*32 .. +32
  const ushort* gsb = Sb + (size_t)((w & 1) * 32 + fr) * 1024 + fk;
  f32x4 acc[2][4] = {};
  f32x4 lacc[2][2] = {};
#define FSTAGE_A(buf, k0)                                     \
  async16(&As[buf][0][t * 8], ga + (k0));                     \
  async16(&As[buf][1][t * 8], ga + (k0) + 32);
#define FSTAGE_B(buf, k0)                                     \
  async16(&Bs[buf][0][t * 8], gb0 + (k0));                    \
  async16(&Bs[buf][0][2048 + t * 8], gb1 + (k0));             \
  async16(&Bs[buf][1][t * 8], gb0 + (k0) + 32);               \
  async16(&Bs[buf][1][2048 + t * 8], gb1 + (k0) + 32);
  // prologue: tiles 0,1 (12 ops); drain tile 0
  FSTAGE_A(0, 0) FSTAGE_B(0, 0)
  FSTAGE_A(1, 64) FSTAGE_B(1, 64)
  asm volatile("s_waitcnt vmcnt(6)" ::: "memory");
  // ---- phases 0..15: main gemm over h + fused logits ----
  for (int it = 0; it < 16; it++) {
    __builtin_amdgcn_s_barrier();
    __builtin_amdgcn_sched_barrier(0);
    const int k0 = it << 6;
    // Sb frags for this phase (compiler-tracked loads, issued first)
    bf16x8 sb00 = *(const bf16x8*)(gsb + k0);
    bf16x8 sb01 = *(const bf16x8*)(gsb + k0 + 32);
    bf16x8 sb10 = *(const bf16x8*)(gsb + k0 + 16384);
    bf16x8 sb11 = *(const bf16x8*)(gsb + k0 + 16384 + 32);
    // prefetch
    if (it <= 13) { const int pb = (it + 2) % 3; FSTAGE_A(pb, k0 + 128) FSTAGE_B(pb, k0 + 128) }
    else if (it == 14) { FSTAGE_B(1, 1024) }
    const int b = it % 3;
    bf16x8 af2[2][2];
#pragma unroll
    for (int kk = 0; kk < 2; kk++) {
      const ushort* pa = &As[b][kk][(wm + fr) * 32 + fk];
      const ushort* pb2 = &Bs[b][kk][(wn + fr) * 32 + fk];
      bf16x8 bfv[4];
#pragma unroll
      for (int mi = 0; mi < 2; mi++) af2[kk][mi] = *(const bf16x8*)(pa + mi * 512);
#pragma unroll
      for (int ni = 0; ni < 4; ni++) bfv[ni] = *(const bf16x8*)(pb2 + ni * 512);
      __builtin_amdgcn_s_setprio(1);
#pragma unroll
      for (int mi = 0; mi < 2; mi++)
#pragma unroll
        for (int ni = 0; ni < 4; ni++)
          acc[mi][ni] = __builtin_amdgcn_mfma_f32_16x16x32_bf16(af2[kk][mi], bfv[ni], acc[mi][ni], 0, 0, 0);
      __builtin_amdgcn_s_setprio(0);
    }
    // wait: Sb regs ready; drains tile(it+1) stage, leaves tile(it+2) in flight
    if (it <= 13)      { asm volatile("s_waitcnt vmcnt(6)" ::: "memory"); }
    else if (it == 14) { asm volatile("s_waitcnt vmcnt(4)" ::: "memory"); }
    else               { asm volatile("s_waitcnt vmcnt(0)" ::: "memory"); }
    __builtin_amdgcn_sched_barrier(0);
    // logits: lacc[mi][ni] += h-frag x Sb-frag
    lacc[0][0] = __builtin_amdgcn_mfma_f32_16x16x32_bf16(af2[0][0], sb00, lacc[0][0], 0, 0, 0);
    lacc[0][1] = __builtin_amdgcn_mfma_f32_16x16x32_bf16(af2[0][0], sb10, lacc[0][1], 0, 0, 0);
    lacc[1][0] = __builtin_amdgcn_mfma_f32_16x16x32_bf16(af2[0][1], sb00, lacc[1][0], 0, 0, 0);
    lacc[1][1] = __builtin_amdgcn_mfma_f32_16x16x32_bf16(af2[0][1], sb10, lacc[1][1], 0, 0, 0);
    lacc[0][0] = __builtin_amdgcn_mfma_f32_16x16x32_bf16(af2[1][0], sb01, lacc[0][0], 0, 0, 0);
    lacc[0][1] = __builtin_amdgcn_mfma_f32_16x16x32_bf16(af2[1][0], sb11, lacc[0][1], 0, 0, 0);
    lacc[1][0] = __builtin_amdgcn_mfma_f32_16x16x32_bf16(af2[1][1], sb01, lacc[1][0], 0, 0, 0);
    lacc[1][1] = __builtin_amdgcn_mfma_f32_16x16x32_bf16(af2[1][1], sb11, lacc[1][1], 0, 0, 0);
  }
  // ---- softmax interlude: logits (this block's 64 rows x 64 s) -> attn ----
  __builtin_amdgcn_s_barrier();          // all waves done reading Bs[0] (tile 15)
  {
    float* lg = (float*)&Bs[0][0][0];    // 16 KB scratch
    const int sbase = (w & 1) * 32;
#pragma unroll
    for (int mi = 0; mi < 2; mi++)
#pragma unroll
      for (int ni = 0; ni < 2; ni++) {
        int s = sbase + ni * 16 + fr;
        int r0 = wm + mi * 16 + fq * 4;
#pragma unroll
        for (int jj = 0; jj < 4; jj++)
          lg[(r0 + jj) * 64 + s] = lacc[mi][ni][jj];
      }
  }
  __syncthreads();
  {
    const int r = t >> 2, q = t & 3;
    float* lg = (float*)&Bs[0][0][0];
    float p[16];
#pragma unroll
    for (int i = 0; i < 16; i++) p[i] = lg[r * 64 + q * 16 + i];
    float mx = p[0];
#pragma unroll
    for (int i = 1; i < 16; i++) mx = fmaxf(mx, p[i]);
    mx = fmaxf(mx, __shfl_xor(mx, 1));
    mx = fmaxf(mx, __shfl_xor(mx, 2));
    float sm = 0.f;
#pragma unroll
    for (int i = 0; i < 16; i++) { p[i] = __expf(p[i] - mx); sm += p[i]; }
    sm += __shfl_xor(sm, 1);
    sm += __shfl_xor(sm, 2);
    float inv = 1.f / sm;
    ushort* at = &As[1][q >> 1][r * 32 + (q & 1) * 16];
#pragma unroll
    for (int i = 0; i < 16; i++) at[i] = f2bf(p[i] * inv);
  }
  __syncthreads();
  // ---- phase 16: attn x SW^T (A from As[1] local, B from Bs[1]) ----
#pragma unroll
  for (int kk = 0; kk < 2; kk++) {
    const ushort* pa = &As[1][kk][(wm + fr) * 32 + fk];
    const ushort* pb2 = &Bs[1][kk][(wn + fr) * 32 + fk];
    bf16x8 af[2], bfv[4];
#pragma unroll
    for (int mi = 0; mi < 2; mi++) af[mi] = *(const bf16x8*)(pa + mi * 512);
#pragma unroll
    for (int ni = 0; ni < 4; ni++) bfv[ni] = *(const bf16x8*)(pb2 + ni * 512);
    __builtin_amdgcn_s_setprio(1);
#pragma unroll
    for (int mi = 0; mi < 2; mi++)
#pragma unroll
      for (int ni = 0; ni < 4; ni++)
        acc[mi][ni] = __builtin_amdgcn_mfma_f32_16x16x32_bf16(af[mi], bfv[ni], acc[mi][ni], 0, 0, 0);
    __builtin_amdgcn_s_setprio(0);
  }
#undef FSTAGE_A
#undef FSTAGE_B
  // ---- epilogue: lane-local LSTM ----
  const int jcol = (((n0 + wn) >> 6) << 4) + fr;
#pragma unroll
  for (int mi = 0; mi < 2; mi++) {
#pragma unroll
    for (int jj = 0; jj < 4; jj++) {
      int row = m0 + wm + mi * 16 + fq * 4 + jj;
      const float* bp = base + (size_t)row * 4096 + (n0 + wn);
      float gi = acc[mi][0][jj] + bp[fr];
      float gf = acc[mi][1][jj] + bp[16 + fr];
      float gg = acc[mi][2][jj] + bp[32 + fr];
      float go = acc[mi][3][jj] + bp[48 + fr];
      size_t cidx = (size_t)row * 1024 + jcol;
      float cv = cbuf[cidx];
      float cn = sigm_(gf) * cv + sigm_(gi) * tanh_(gg);
      float hn = sigm_(go) * tanh_(cn) + query[cidx];
      cbuf[cidx] = cn;
      Xout[cidx] = f2bf(hn);
      if (outp) outp[cidx] = hn;
    }
  }
}

extern "C" void kernel_launch(void* const* d_in, const int* in_sizes, int n_in,
                              void* d_out, int out_size, void* d_ws, size_t ws_size,
                              hipStream_t stream) {
  const float* query   = (const float*)d_in[0];
  const float* support = (const float*)d_in[1];
  const float* W_ih    = (const float*)d_in[2];
  const float* W_hh    = (const float*)d_in[3];
  const float* b_ih    = (const float*)d_in[4];
  const float* b_hh    = (const float*)d_in[5];
  float* out = (float*)d_out;

  char* ws = (char*)d_ws;
  size_t off = 0;
  auto alloc = [&](size_t bytes) {
    void* p = ws + off;
    off += (bytes + 255) & ~(size_t)255;
    return p;
  };
  ushort* Wq_bf  = (ushort*)alloc((size_t)4096 * 1024 * 2);
  ushort* Wcomb  = (ushort*)alloc((size_t)4096 * 1088 * 2);
  ushort* Wr_bf  = (ushort*)alloc((size_t)4096 * 1024 * 2);
  ushort* Sb     = (ushort*)alloc((size_t)64 * 1024 * 2);
  float*  bias_p = (float*) alloc((size_t)4096 * 4);
  float*  base   = (float*) alloc((size_t)1024 * 4096 * 4);
  ushort* X0     = (ushort*)alloc((size_t)1024 * 1024 * 2);
  ushort* X1     = (ushort*)alloc((size_t)1024 * 1024 * 2);
  float*  c      = (float*) alloc((size_t)1024 * 1024 * 4);

  prep_kernel<<<16384, 256, 0, stream>>>(query, support, W_ih, W_hh, b_ih, b_hh,
                                         Wq_bf, Wcomb, bias_p, X0, c, Wr_bf, Sb);
  sw_mfma<<<32, 256, 0, stream>>>(Wr_bf, Sb, Wcomb);
  gemm_base<<<512, 256, 0, stream>>>(X0, Wq_bf, bias_p, base);
  for (int step = 0; step < 64; step++) {
    ushort* Xc = (step & 1) ? X1 : X0;
    ushort* Xn = (step & 1) ? X0 : X1;
    gemm_fused<<<512, 256, 0, stream>>>(Xc, Wcomb, Sb, base,
                                        c, query, Xn,
                                        (step == 63) ? out : nullptr);
  }
}